// Round 1
// baseline (13.098 us; speedup 1.0000x reference)
//
#include <hip/hip_runtime.h>
#include <math.h>

#define NROWS 8192
#define KP1 17

// One 32-lane group per row: lanes 0..16 gather, shuffle-reduce, lane 0 writes.
__global__ __launch_bounds__(256) void gather_sum_kernel(
    const float* __restrict__ data,
    const int* __restrict__ nidx,
    float* __restrict__ a_raw)
{
    int tid   = blockIdx.x * blockDim.x + threadIdx.x;
    int row   = tid >> 5;          // 32 lanes per row
    int lane  = tid & 31;
    if (row >= NROWS) return;

    float v = 0.0f;
    if (lane < KP1) {
        int c = nidx[row * KP1 + lane];
        v = data[(size_t)row * NROWS + (size_t)c];
    }
    // reduce across the 32-lane group
    #pragma unroll
    for (int off = 16; off > 0; off >>= 1)
        v += __shfl_down(v, off, 32);

    if (lane == 0) a_raw[row] = v;
}

// Single-block softmax over NROWS floats. 1024 threads x 8 elems each.
__global__ __launch_bounds__(1024) void softmax_kernel(
    const float* __restrict__ a_raw,
    float* __restrict__ alpha)
{
    __shared__ float red[16];
    const int t    = threadIdx.x;
    const int wave = t >> 6;
    const int lane = t & 63;

    float vals[8];
    float m = -INFINITY;
    #pragma unroll
    for (int i = 0; i < 8; ++i) {
        vals[i] = a_raw[t + i * 1024];
        m = fmaxf(m, vals[i]);
    }
    // wave-level max
    #pragma unroll
    for (int off = 32; off > 0; off >>= 1)
        m = fmaxf(m, __shfl_down(m, off, 64));
    if (lane == 0) red[wave] = m;
    __syncthreads();
    if (wave == 0) {
        float mm = (lane < 16) ? red[lane] : -INFINITY;
        #pragma unroll
        for (int off = 8; off > 0; off >>= 1)
            mm = fmaxf(mm, __shfl_down(mm, off, 64));
        if (lane == 0) red[0] = mm;
    }
    __syncthreads();
    m = red[0];
    __syncthreads();   // red[] reused below

    float s = 0.0f;
    #pragma unroll
    for (int i = 0; i < 8; ++i) {
        vals[i] = expf(vals[i] - m);
        s += vals[i];
    }
    #pragma unroll
    for (int off = 32; off > 0; off >>= 1)
        s += __shfl_down(s, off, 64);
    if (lane == 0) red[wave] = s;
    __syncthreads();
    if (wave == 0) {
        float ss = (lane < 16) ? red[lane] : 0.0f;
        #pragma unroll
        for (int off = 8; off > 0; off >>= 1)
            ss += __shfl_down(ss, off, 64);
        if (lane == 0) red[0] = ss;
    }
    __syncthreads();
    const float inv = 1.0f / red[0];
    #pragma unroll
    for (int i = 0; i < 8; ++i)
        alpha[t + i * 1024] = vals[i] * inv;
}

extern "C" void kernel_launch(void* const* d_in, const int* in_sizes, int n_in,
                              void* d_out, int out_size, void* d_ws, size_t ws_size,
                              hipStream_t stream) {
    const float* data = (const float*)d_in[0];
    const int*   nidx = (const int*)d_in[1];
    float* alpha = (float*)d_out;            // output 0: alpha (8192)
    float* a_raw = (float*)d_out + NROWS;    // output 1: A_raw (8192)

    // 32 lanes per row -> 8192*32 threads / 256 = 1024 blocks
    gather_sum_kernel<<<(NROWS * 32) / 256, 256, 0, stream>>>(data, nidx, a_raw);
    softmax_kernel<<<1, 1024, 0, stream>>>(a_raw, alpha);
}